// Round 1
// baseline (1246.101 us; speedup 1.0000x reference)
//
#include <hip/hip_runtime.h>
#include <hip/hip_bf16.h>
#include <math.h>

typedef __attribute__((ext_vector_type(8))) short bf16x8;
typedef __attribute__((ext_vector_type(4))) float f32x4;
typedef __attribute__((ext_vector_type(4))) unsigned int u32x4;

#define NP 16384
#define HWFULL 65536

__device__ __forceinline__ unsigned short f2bf(float f){
    union { float f; unsigned int u; } v; v.f = f;
    unsigned int u = v.u;
    u += 0x7fffu + ((u >> 16) & 1u);
    return (unsigned short)(u >> 16);
}
__device__ __forceinline__ float bf2f(unsigned short h){
    union { unsigned int u; float f; } v; v.u = ((unsigned int)h) << 16;
    return v.f;
}
__device__ __forceinline__ unsigned int pk2(float a, float b){
    return (unsigned int)f2bf(a) | ((unsigned int)f2bf(b) << 16);
}

// ---- K0: fp32 -> bf16 weight conversion ----
__global__ void k_convert(const float* __restrict__ s, unsigned short* __restrict__ d, int n){
    int i = blockIdx.x * 256 + threadIdx.x;
    if (i < n) d[i] = f2bf(s[i]);
}

// ---- K1: qkv 1x1 conv (bf16 MFMA GEMM) fused with 2x2 maxpool ----
// grid (512, 12): bx -> (y2 = bx>>2, x2blk = bx&3); by -> (b = by/3, ocblk = by%3)
// C tile: 192 oc x 128 positions (2 rows y=2*y2,2*y2+1 of 64 cols) -> 32 pooled outputs
__global__ void k_qkvpool(const float* __restrict__ x, const unsigned short* __restrict__ Wbf,
                          unsigned short* __restrict__ qkvp){
    __shared__ unsigned short Al[192*72];  // [oc][k(64)+pad8], 16B-aligned rows (144 B)
    __shared__ unsigned short Bl[128*72];  // [pos][k(64)+pad8]
    int tid = threadIdx.x;
    int lane = tid & 63, wv = tid >> 6;
    int n16 = lane & 15, quad = lane >> 4;
    int bx = blockIdx.x;
    int y2 = bx >> 2, x2blk = bx & 3;
    int by = blockIdx.y;
    int b = by / 3, ocblk = by % 3;

    f32x4 acc[3][8];
    #pragma unroll
    for (int j=0;j<3;j++)
      #pragma unroll
      for (int s=0;s<8;s++)
        acc[j][s] = (f32x4){0.f,0.f,0.f,0.f};

    for (int cc=0; cc<3; cc++){
        int ic0 = cc*64;
        // stage A (weights, already bf16): 192 rows x 8 granules of 8 elems
        #pragma unroll
        for (int j=0;j<6;j++){
            int idx = tid + j*256;
            int r = idx >> 3, g = idx & 7;
            const unsigned short* p = Wbf + ((ocblk*192 + r)*192 + ic0 + g*8);
            *(u32x4*)&Al[r*72 + g*8] = *(const u32x4*)p;
        }
        // stage B: transpose-gather x[ic][pos] -> Bl[pos][ic], fp32->bf16
        #pragma unroll
        for (int j=0;j<4;j++){
            int idx = tid + j*256;
            int g = idx >> 7, w = idx & 127;       // w: 0..63 row y, 64..127 row y+1
            int y = y2*2 + (w >> 6);
            int xc = x2blk*64 + (w & 63);
            const float* xp = x + (size_t)(b*192 + ic0 + g*8) * HWFULL + y*256 + xc;
            float v0 = xp[0];
            float v1 = xp[(size_t)1*HWFULL];
            float v2 = xp[(size_t)2*HWFULL];
            float v3 = xp[(size_t)3*HWFULL];
            float v4 = xp[(size_t)4*HWFULL];
            float v5 = xp[(size_t)5*HWFULL];
            float v6 = xp[(size_t)6*HWFULL];
            float v7 = xp[(size_t)7*HWFULL];
            u32x4 pk;
            pk.x = pk2(v0,v1); pk.y = pk2(v2,v3); pk.z = pk2(v4,v5); pk.w = pk2(v6,v7);
            *(u32x4*)&Bl[w*72 + g*8] = pk;
        }
        __syncthreads();
        #pragma unroll
        for (int kc=0;kc<2;kc++){
            int ko = kc*32 + quad*8;
            bf16x8 af[3], bfr[8];
            #pragma unroll
            for (int j=0;j<3;j++) af[j] = *(const bf16x8*)&Al[((wv*3+j)*16 + n16)*72 + ko];
            #pragma unroll
            for (int s=0;s<8;s++) bfr[s] = *(const bf16x8*)&Bl[(s*16 + n16)*72 + ko];
            #pragma unroll
            for (int j=0;j<3;j++)
              #pragma unroll
              for (int s=0;s<8;s++)
                acc[j][s] = __builtin_amdgcn_mfma_f32_16x16x32_bf16(af[j], bfr[s], acc[j][s], 0,0,0);
        }
        __syncthreads();
    }
    // epilogue: maxpool (strip s with s+4 = rows y,y+1; lane^1 = x,x+1), store bf16
    int tbase = y2*128 + x2blk*32;
    #pragma unroll
    for (int j=0;j<3;j++){
        int ocg = b*576 + ocblk*192 + (wv*3+j)*16 + quad*4;
        #pragma unroll
        for (int sp=0;sp<4;sp++){
            #pragma unroll
            for (int r=0;r<4;r++){
                float v = fmaxf(acc[j][sp][r], acc[j][sp+4][r]);
                float o = __shfl_xor(v, 1, 64);
                v = fmaxf(v, o);
                if ((n16 & 1) == 0){
                    int t = sp*8 + (n16 >> 1);
                    qkvp[(size_t)(ocg + r)*NP + tbase + t] = f2bf(v);
                }
            }
        }
    }
}

// ---- K2: depthwise 3x3 SAME conv + per-channel sum-of-squares (q,k only) ----
// grid (8, 576, 4), block 256
__global__ void k_dwconv(const unsigned short* __restrict__ qkvp, const float* __restrict__ dww,
                         float* __restrict__ dwout, float* __restrict__ sumsq){
    __shared__ float sl[18*130];
    int tid = threadIdx.x;
    int y0 = blockIdx.x * 16;
    int ch = blockIdx.y;
    int b  = blockIdx.z;
    const unsigned short* in = qkvp + (size_t)(b*576 + ch) * NP;
    #pragma unroll
    for (int j=0;j<10;j++){
        int idx = tid + j*256;
        if (idx < 18*130){
            int row = idx / 130;
            int col = idx % 130;
            int gy = y0 - 1 + row;
            int gx = col - 1;
            float v = 0.f;
            if (gy >= 0 && gy < 128 && gx >= 0 && gx < 128)
                v = bf2f(in[gy*128 + gx]);
            sl[idx] = v;
        }
    }
    float w0 = dww[ch*9+0], w1 = dww[ch*9+1], w2 = dww[ch*9+2];
    float w3 = dww[ch*9+3], w4 = dww[ch*9+4], w5 = dww[ch*9+5];
    float w6 = dww[ch*9+6], w7 = dww[ch*9+7], w8 = dww[ch*9+8];
    __syncthreads();
    float* outp = dwout + (size_t)(b*576 + ch) * NP;
    int col = tid & 127, half = tid >> 7;
    float ssq = 0.f;
    #pragma unroll
    for (int i=0;i<8;i++){
        int ry = half*8 + i;
        const float* r0 = &sl[ry*130 + col];
        float a = r0[0]*w0   + r0[1]*w1   + r0[2]*w2
                + r0[130]*w3 + r0[131]*w4 + r0[132]*w5
                + r0[260]*w6 + r0[261]*w7 + r0[262]*w8;
        outp[(y0+ry)*128 + col] = a;
        ssq += a*a;
    }
    if (ch < 384){
        #pragma unroll
        for (int off=32; off>0; off>>=1) ssq += __shfl_down(ssq, off, 64);
        if ((tid & 63) == 0) atomicAdd(&sumsq[b*384 + ch], ssq);
    }
}

// ---- K3a: raw attention gram matrix, K-split with atomics ----
// grid (128, 6, 4), block 256
__global__ void k_attnraw(const float* __restrict__ dwout, float* __restrict__ attn){
    __shared__ float ql[32*130];
    __shared__ float kl[32*130];
    int tid = threadIdx.x;
    int n0 = blockIdx.x * 128;
    int h = blockIdx.y, b = blockIdx.z;
    const float* qb = dwout + (size_t)(b*576 + h*32)*NP + n0;
    const float* kb = dwout + (size_t)(b*576 + 192 + h*32)*NP + n0;
    #pragma unroll
    for (int j=0;j<16;j++){
        int idx = tid + j*256;
        int r = idx >> 7, c = idx & 127;
        ql[r*130 + c] = qb[(size_t)r*NP + c];
        kl[r*130 + c] = kb[(size_t)r*NP + c];
    }
    __syncthreads();
    int cr = tid >> 3, dg = tid & 7;
    float a0=0,a1=0,a2=0,a3=0;
    for (int n=0;n<128;n++){
        float qv = ql[cr*130 + n];
        a0 += qv * kl[(dg*4+0)*130 + n];
        a1 += qv * kl[(dg*4+1)*130 + n];
        a2 += qv * kl[(dg*4+2)*130 + n];
        a3 += qv * kl[(dg*4+3)*130 + n];
    }
    float* ap = attn + (size_t)(b*6+h)*1024 + cr*32 + dg*4;
    atomicAdd(ap+0, a0); atomicAdd(ap+1, a1); atomicAdd(ap+2, a2); atomicAdd(ap+3, a3);
}

// ---- K3b: normalize, temperature, 4x top-k masked softmax, combine with a1..a4 ----
// grid 24, block 64
__global__ void k_mask_softmax(const float* __restrict__ attn, const float* __restrict__ sumsq,
                               const float* __restrict__ temp,
                               const float* __restrict__ A1, const float* __restrict__ A2,
                               const float* __restrict__ A3, const float* __restrict__ A4,
                               float* __restrict__ comb){
    __shared__ float Am[32][33];
    __shared__ float Em[32][33];
    __shared__ float qn[32], kn[32];
    __shared__ unsigned char Rm[32][32];
    int t = threadIdx.x;
    int bh = blockIdx.x;
    int b = bh / 6, h = bh % 6;
    if (t < 32){
        qn[t] = fmaxf(sqrtf(sumsq[b*384 + h*32 + t]), 1e-12f);
        kn[t] = fmaxf(sqrtf(sumsq[b*384 + 192 + h*32 + t]), 1e-12f);
    }
    __syncthreads();
    float tv = temp[h];
    const float* ap = attn + (size_t)bh*1024;
    #pragma unroll
    for (int j=0;j<16;j++){
        int idx = t + j*64;
        int c = idx >> 5, d = idx & 31;
        Am[c][d] = ap[idx] * tv / (qn[c]*kn[d]);
    }
    __syncthreads();
    if (t < 32){
        int c = t;
        float m = -1e30f;
        for (int d=0;d<32;d++) m = fmaxf(m, Am[c][d]);
        for (int d=0;d<32;d++) Em[c][d] = expf(Am[c][d] - m);
        for (int d=0;d<32;d++){
            float ad = Am[c][d];
            int rk = 0;
            for (int dd=0;dd<32;dd++){
                float av = Am[c][dd];
                rk += (av > ad) || (av == ad && dd < d);
            }
            Rm[c][d] = (unsigned char)rk;
        }
        float d0=0,d1=0,d2=0,d3=0;
        for (int d=0;d<32;d++){
            float e = Em[c][d]; int rk = Rm[c][d];
            if (rk < 16) d0 += e;
            if (rk < 21) d1 += e;
            if (rk < 24) d2 += e;
            if (rk < 25) d3 += e;
        }
        float f0 = A1[0]/d0, f1 = A2[0]/d1, f2 = A3[0]/d2, f3 = A4[0]/d3;
        float* cp = comb + (size_t)bh*1024 + c*32;
        for (int d=0;d<32;d++){
            int rk = Rm[c][d];
            float s = (rk<16?f0:0.f) + (rk<21?f1:0.f) + (rk<24?f2:0.f) + (rk<25?f3:0.f);
            cp[d] = Em[c][d] * s;
        }
    }
}

// ---- K4a: out = comb @ v, exact GeLU, store TRANSPOSED g[b][n][192] bf16 ----
// grid (64, 4), block 256
__global__ void k_applyv(const float* __restrict__ dwout, const float* __restrict__ comb,
                         unsigned short* __restrict__ gT){
    __shared__ float cm[6144];
    int tid = threadIdx.x;
    int b = blockIdx.y;
    int n = blockIdx.x*256 + tid;
    #pragma unroll
    for (int j=0;j<24;j++) cm[tid + j*256] = comb[b*6144 + tid + j*256];
    __syncthreads();
    const float* vb = dwout + (size_t)(b*576 + 384)*NP + n;
    unsigned short* gp = gT + (size_t)(b*NP + n)*192;
    #pragma unroll 1
    for (int h=0;h<6;h++){
        float v[32];
        #pragma unroll
        for (int d=0;d<32;d++) v[d] = vb[(size_t)(h*32+d)*NP];
        const float* chp = &cm[h*1024];
        #pragma unroll 1
        for (int cg=0;cg<4;cg++){
            float s[8];
            #pragma unroll
            for (int i=0;i<8;i++){
                const float* crow = chp + (cg*8+i)*32;
                float acc = 0.f;
                #pragma unroll
                for (int d=0;d<32;d++) acc += crow[d]*v[d];
                s[i] = 0.5f*acc*(1.f + erff(acc*0.70710678118654752f));
            }
            u32x4 pk;
            pk.x = pk2(s[0],s[1]); pk.y = pk2(s[2],s[3]);
            pk.z = pk2(s[4],s[5]); pk.w = pk2(s[6],s[7]);
            *(u32x4*)(gp + h*32 + cg*8) = pk;
        }
    }
}

// ---- K4b: proj GEMM at low res (M=192,K=192,N=128/block) + nearest 2x upsample ----
// grid (128, 4), block 256
__global__ void k_proj(const unsigned short* __restrict__ gT, const unsigned short* __restrict__ Pbf,
                       float* __restrict__ out){
    __shared__ unsigned short Al[192*72];
    __shared__ unsigned short Bl[128*72];
    int tid = threadIdx.x;
    int lane = tid & 63, wv = tid >> 6;
    int n16 = lane & 15, quad = lane >> 4;
    int y2 = blockIdx.x, b = blockIdx.y;

    f32x4 acc[3][8];
    #pragma unroll
    for (int j=0;j<3;j++)
      #pragma unroll
      for (int s=0;s<8;s++)
        acc[j][s] = (f32x4){0.f,0.f,0.f,0.f};

    for (int cc=0; cc<3; cc++){
        int ic0 = cc*64;
        #pragma unroll
        for (int j=0;j<6;j++){
            int idx = tid + j*256;
            int r = idx >> 3, g = idx & 7;
            *(u32x4*)&Al[r*72 + g*8] = *(const u32x4*)(Pbf + (r*192 + ic0 + g*8));
        }
        #pragma unroll
        for (int j=0;j<4;j++){
            int idx = tid + j*256;
            int r = idx >> 3, g = idx & 7;
            *(u32x4*)&Bl[r*72 + g*8] =
                *(const u32x4*)(gT + ((size_t)(b*NP + y2*128 + r)*192 + ic0 + g*8));
        }
        __syncthreads();
        #pragma unroll
        for (int kc=0;kc<2;kc++){
            int ko = kc*32 + quad*8;
            bf16x8 af[3], bfr[8];
            #pragma unroll
            for (int j=0;j<3;j++) af[j] = *(const bf16x8*)&Al[((wv*3+j)*16 + n16)*72 + ko];
            #pragma unroll
            for (int s=0;s<8;s++) bfr[s] = *(const bf16x8*)&Bl[(s*16 + n16)*72 + ko];
            #pragma unroll
            for (int j=0;j<3;j++)
              #pragma unroll
              for (int s=0;s<8;s++)
                acc[j][s] = __builtin_amdgcn_mfma_f32_16x16x32_bf16(af[j], bfr[s], acc[j][s], 0,0,0);
        }
        __syncthreads();
    }
    #pragma unroll
    for (int j=0;j<3;j++){
        int oc = (wv*3+j)*16 + quad*4;
        #pragma unroll
        for (int sp=0;sp<8;sp++){
            int x2 = sp*16 + n16;
            #pragma unroll
            for (int r=0;r<4;r++){
                float v = acc[j][sp][r];
                size_t o = ((size_t)(b*192 + oc + r)*256 + 2*y2)*256 + 2*x2;
                float2 val = make_float2(v, v);
                *(float2*)(out + o) = val;
                *(float2*)(out + o + 256) = val;
            }
        }
    }
}

extern "C" void kernel_launch(void* const* d_in, const int* in_sizes, int n_in,
                              void* d_out, int out_size, void* d_ws, size_t ws_size,
                              hipStream_t stream){
    const float* x     = (const float*)d_in[0];
    const float* temp  = (const float*)d_in[1];
    const float* qkvw  = (const float*)d_in[2];
    const float* dww   = (const float*)d_in[3];
    const float* projw = (const float*)d_in[4];
    const float* A1    = (const float*)d_in[5];
    const float* A2    = (const float*)d_in[6];
    const float* A3    = (const float*)d_in[7];
    const float* A4    = (const float*)d_in[8];
    float* out = (float*)d_out;
    char* ws = (char*)d_ws;

    // workspace layout (bytes)
    float*          dwout = (float*)ws;                              // 150,994,944
    unsigned short* qkvp  = (unsigned short*)(ws + 150994944ull);    // 75,497,472
    unsigned short* gT    = (unsigned short*)(ws + 150994944ull);    // overlaps qkvp (dead by then)
    unsigned short* Wbf   = (unsigned short*)(ws + 226492416ull);    // 221,184
    unsigned short* Pbf   = (unsigned short*)(ws + 226713600ull);    // 73,728
    float*          attn  = (float*)(ws + 226787328ull);             // 98,304
    float*          comb  = (float*)(ws + 226885632ull);             // 98,304
    float*          sumsq = (float*)(ws + 226983936ull);             // 6,144

    hipMemsetAsync(attn, 0, 98304, stream);
    hipMemsetAsync(sumsq, 0, 6144, stream);
    k_convert<<<dim3((110592+255)/256), dim3(256), 0, stream>>>(qkvw, Wbf, 110592);
    k_convert<<<dim3((36864+255)/256), dim3(256), 0, stream>>>(projw, Pbf, 36864);
    k_qkvpool<<<dim3(512,12), dim3(256), 0, stream>>>(x, Wbf, qkvp);
    k_dwconv<<<dim3(8,576,4), dim3(256), 0, stream>>>(qkvp, dww, dwout, sumsq);
    k_attnraw<<<dim3(128,6,4), dim3(256), 0, stream>>>(dwout, attn);
    k_mask_softmax<<<dim3(24), dim3(64), 0, stream>>>(attn, sumsq, temp, A1, A2, A3, A4, comb);
    k_applyv<<<dim3(64,4), dim3(256), 0, stream>>>(dwout, comb, gT);
    k_proj<<<dim3(128,4), dim3(256), 0, stream>>>(gT, Pbf, out);
}

// Round 2
// 746.834 us; speedup vs baseline: 1.6685x; 1.6685x over previous
//
#include <hip/hip_runtime.h>
#include <hip/hip_bf16.h>
#include <math.h>

typedef __attribute__((ext_vector_type(8))) short bf16x8;
typedef __attribute__((ext_vector_type(4))) float f32x4;
typedef __attribute__((ext_vector_type(4))) unsigned int u32x4;

#define NP 16384
#define HWFULL 65536

__device__ __forceinline__ unsigned short f2bf(float f){
    union { float f; unsigned int u; } v; v.f = f;
    unsigned int u = v.u;
    u += 0x7fffu + ((u >> 16) & 1u);
    return (unsigned short)(u >> 16);
}
__device__ __forceinline__ float bf2f(unsigned short h){
    union { unsigned int u; float f; } v; v.u = ((unsigned int)h) << 16;
    return v.f;
}
__device__ __forceinline__ unsigned int pk2(float a, float b){
    return (unsigned int)f2bf(a) | ((unsigned int)f2bf(b) << 16);
}

// ---- K0: fp32 -> bf16 weight conversion ----
__global__ void k_convert(const float* __restrict__ s, unsigned short* __restrict__ d, int n){
    int i = blockIdx.x * 256 + threadIdx.x;
    if (i < n) d[i] = f2bf(s[i]);
}

// ---- K1: qkv 1x1 conv (bf16 MFMA GEMM) fused with 2x2 maxpool ----
// v2: x read ONCE per block (full-K B-tile persistent in LDS, all 3 oc-blocks
// looped internally), epilogue staged through LDS -> full-line coalesced stores.
// grid (512, 4): bx -> (y2 = bx>>2, x2blk = bx&3); by = b
__global__ __launch_bounds__(256, 2)
void k_qkvpool(const float* __restrict__ x, const unsigned short* __restrict__ Wbf,
               unsigned short* __restrict__ qkvp){
    __shared__ unsigned short Bl[128*200];  // [pos][K=192 + pad8] bf16, persistent
    __shared__ unsigned short Al[192*72];   // [oc][k-chunk 64 + pad8]; aliased as epilogue buffer
    int tid = threadIdx.x;
    int lane = tid & 63, wv = tid >> 6;
    int n16 = lane & 15, quad = lane >> 4;
    int bx = blockIdx.x;
    int y2 = bx >> 2, x2blk = bx & 3;
    int b = blockIdx.y;

    // ---- stage B: transpose-gather x[ic][pos] -> Bl[pos][ic], fp32->bf16, full K ----
    #pragma unroll 3
    for (int j=0;j<12;j++){
        int idx = tid + j*256;
        int g = idx >> 7, w = idx & 127;       // g: ic granule of 8; w: 0..63 row y, 64..127 row y+1
        int y = y2*2 + (w >> 6);
        int xc = x2blk*64 + (w & 63);
        const float* xp = x + (size_t)(b*192 + g*8) * HWFULL + y*256 + xc;
        float v0 = xp[0];
        float v1 = xp[(size_t)1*HWFULL];
        float v2 = xp[(size_t)2*HWFULL];
        float v3 = xp[(size_t)3*HWFULL];
        float v4 = xp[(size_t)4*HWFULL];
        float v5 = xp[(size_t)5*HWFULL];
        float v6 = xp[(size_t)6*HWFULL];
        float v7 = xp[(size_t)7*HWFULL];
        u32x4 pk;
        pk.x = pk2(v0,v1); pk.y = pk2(v2,v3); pk.z = pk2(v4,v5); pk.w = pk2(v6,v7);
        *(u32x4*)&Bl[w*200 + g*8] = pk;
    }
    __syncthreads();

    for (int ocblk=0; ocblk<3; ocblk++){
        f32x4 acc[3][8];
        #pragma unroll
        for (int j=0;j<3;j++)
          #pragma unroll
          for (int s=0;s<8;s++)
            acc[j][s] = (f32x4){0.f,0.f,0.f,0.f};

        for (int cc=0; cc<3; cc++){
            __syncthreads();   // prev mfma / epilogue reads of Al done before overwrite
            #pragma unroll
            for (int j=0;j<6;j++){
                int idx = tid + j*256;
                int r = idx >> 3, g = idx & 7;
                *(u32x4*)&Al[r*72 + g*8] =
                    *(const u32x4*)(Wbf + ((ocblk*192 + r)*192 + cc*64 + g*8));
            }
            __syncthreads();
            #pragma unroll
            for (int kc=0;kc<2;kc++){
                int ako = kc*32 + quad*8;
                int bko = cc*64 + ako;
                bf16x8 af[3], bfr[8];
                #pragma unroll
                for (int j=0;j<3;j++) af[j] = *(const bf16x8*)&Al[((wv*3+j)*16 + n16)*72 + ako];
                #pragma unroll
                for (int s=0;s<8;s++) bfr[s] = *(const bf16x8*)&Bl[(s*16 + n16)*200 + bko];
                #pragma unroll
                for (int j=0;j<3;j++)
                  #pragma unroll
                  for (int s=0;s<8;s++)
                    acc[j][s] = __builtin_amdgcn_mfma_f32_16x16x32_bf16(af[j], bfr[s], acc[j][s], 0,0,0);
            }
        }
        __syncthreads();   // all mfma reads done; Al becomes epilogue buffer
        // ---- epilogue: 2x2 maxpool into LDS (strip sp & sp+4 = rows y,y+1; lane^1 = x,x+1)
        unsigned short* Ep = Al;   // [oc 192][36] pooled bf16
        #pragma unroll
        for (int j=0;j<3;j++){
            int ocr = (wv*3+j)*16 + quad*4;
            #pragma unroll
            for (int sp=0;sp<4;sp++){
                #pragma unroll
                for (int r=0;r<4;r++){
                    float v = fmaxf(acc[j][sp][r], acc[j][sp+4][r]);
                    float o = __shfl_xor(v, 1, 64);
                    v = fmaxf(v, o);
                    if ((n16 & 1) == 0)
                        Ep[(ocr + r)*36 + sp*8 + (n16 >> 1)] = f2bf(v);
                }
            }
        }
        __syncthreads();
        // ---- cooperative coalesced store: 192 rows x 32 shorts (64B/row) ----
        size_t rowbase = (size_t)(b*576 + ocblk*192)*NP + y2*128 + x2blk*32;
        #pragma unroll
        for (int it=0; it<6; it++){
            int c = tid + it*256;
            int row = c >> 3, seg = c & 7;
            uint2 vv = *(const uint2*)&Ep[row*36 + seg*4];
            *(uint2*)(qkvp + rowbase + (size_t)row*NP + seg*4) = vv;
        }
    }
}

// ---- K2: depthwise 3x3 SAME conv + per-channel sum-of-squares (q,k only) ----
// grid (8, 576, 4), block 256
__global__ void k_dwconv(const unsigned short* __restrict__ qkvp, const float* __restrict__ dww,
                         float* __restrict__ dwout, float* __restrict__ sumsq){
    __shared__ float sl[18*130];
    int tid = threadIdx.x;
    int y0 = blockIdx.x * 16;
    int ch = blockIdx.y;
    int b  = blockIdx.z;
    const unsigned short* in = qkvp + (size_t)(b*576 + ch) * NP;
    #pragma unroll
    for (int j=0;j<10;j++){
        int idx = tid + j*256;
        if (idx < 18*130){
            int row = idx / 130;
            int col = idx % 130;
            int gy = y0 - 1 + row;
            int gx = col - 1;
            float v = 0.f;
            if (gy >= 0 && gy < 128 && gx >= 0 && gx < 128)
                v = bf2f(in[gy*128 + gx]);
            sl[idx] = v;
        }
    }
    float w0 = dww[ch*9+0], w1 = dww[ch*9+1], w2 = dww[ch*9+2];
    float w3 = dww[ch*9+3], w4 = dww[ch*9+4], w5 = dww[ch*9+5];
    float w6 = dww[ch*9+6], w7 = dww[ch*9+7], w8 = dww[ch*9+8];
    __syncthreads();
    float* outp = dwout + (size_t)(b*576 + ch) * NP;
    int col = tid & 127, half = tid >> 7;
    float ssq = 0.f;
    #pragma unroll
    for (int i=0;i<8;i++){
        int ry = half*8 + i;
        const float* r0 = &sl[ry*130 + col];
        float a = r0[0]*w0   + r0[1]*w1   + r0[2]*w2
                + r0[130]*w3 + r0[131]*w4 + r0[132]*w5
                + r0[260]*w6 + r0[261]*w7 + r0[262]*w8;
        outp[(y0+ry)*128 + col] = a;
        ssq += a*a;
    }
    if (ch < 384){
        #pragma unroll
        for (int off=32; off>0; off>>=1) ssq += __shfl_down(ssq, off, 64);
        if ((tid & 63) == 0) atomicAdd(&sumsq[b*384 + ch], ssq);
    }
}

// ---- K3a: raw attention gram matrix, K-split with atomics ----
// grid (128, 6, 4), block 256
__global__ void k_attnraw(const float* __restrict__ dwout, float* __restrict__ attn){
    __shared__ float ql[32*130];
    __shared__ float kl[32*130];
    int tid = threadIdx.x;
    int n0 = blockIdx.x * 128;
    int h = blockIdx.y, b = blockIdx.z;
    const float* qb = dwout + (size_t)(b*576 + h*32)*NP + n0;
    const float* kb = dwout + (size_t)(b*576 + 192 + h*32)*NP + n0;
    #pragma unroll
    for (int j=0;j<16;j++){
        int idx = tid + j*256;
        int r = idx >> 7, c = idx & 127;
        ql[r*130 + c] = qb[(size_t)r*NP + c];
        kl[r*130 + c] = kb[(size_t)r*NP + c];
    }
    __syncthreads();
    int cr = tid >> 3, dg = tid & 7;
    float a0=0,a1=0,a2=0,a3=0;
    for (int n=0;n<128;n++){
        float qv = ql[cr*130 + n];
        a0 += qv * kl[(dg*4+0)*130 + n];
        a1 += qv * kl[(dg*4+1)*130 + n];
        a2 += qv * kl[(dg*4+2)*130 + n];
        a3 += qv * kl[(dg*4+3)*130 + n];
    }
    float* ap = attn + (size_t)(b*6+h)*1024 + cr*32 + dg*4;
    atomicAdd(ap+0, a0); atomicAdd(ap+1, a1); atomicAdd(ap+2, a2); atomicAdd(ap+3, a3);
}

// ---- K3b: normalize, temperature, 4x top-k masked softmax, combine with a1..a4 ----
// grid 24, block 64
__global__ void k_mask_softmax(const float* __restrict__ attn, const float* __restrict__ sumsq,
                               const float* __restrict__ temp,
                               const float* __restrict__ A1, const float* __restrict__ A2,
                               const float* __restrict__ A3, const float* __restrict__ A4,
                               float* __restrict__ comb){
    __shared__ float Am[32][33];
    __shared__ float Em[32][33];
    __shared__ float qn[32], kn[32];
    __shared__ unsigned char Rm[32][32];
    int t = threadIdx.x;
    int bh = blockIdx.x;
    int b = bh / 6, h = bh % 6;
    if (t < 32){
        qn[t] = fmaxf(sqrtf(sumsq[b*384 + h*32 + t]), 1e-12f);
        kn[t] = fmaxf(sqrtf(sumsq[b*384 + 192 + h*32 + t]), 1e-12f);
    }
    __syncthreads();
    float tv = temp[h];
    const float* ap = attn + (size_t)bh*1024;
    #pragma unroll
    for (int j=0;j<16;j++){
        int idx = t + j*64;
        int c = idx >> 5, d = idx & 31;
        Am[c][d] = ap[idx] * tv / (qn[c]*kn[d]);
    }
    __syncthreads();
    if (t < 32){
        int c = t;
        float m = -1e30f;
        for (int d=0;d<32;d++) m = fmaxf(m, Am[c][d]);
        for (int d=0;d<32;d++) Em[c][d] = expf(Am[c][d] - m);
        for (int d=0;d<32;d++){
            float ad = Am[c][d];
            int rk = 0;
            for (int dd=0;dd<32;dd++){
                float av = Am[c][dd];
                rk += (av > ad) || (av == ad && dd < d);
            }
            Rm[c][d] = (unsigned char)rk;
        }
        float d0=0,d1=0,d2=0,d3=0;
        for (int d=0;d<32;d++){
            float e = Em[c][d]; int rk = Rm[c][d];
            if (rk < 16) d0 += e;
            if (rk < 21) d1 += e;
            if (rk < 24) d2 += e;
            if (rk < 25) d3 += e;
        }
        float f0 = A1[0]/d0, f1 = A2[0]/d1, f2 = A3[0]/d2, f3 = A4[0]/d3;
        float* cp = comb + (size_t)bh*1024 + c*32;
        for (int d=0;d<32;d++){
            int rk = Rm[c][d];
            float s = (rk<16?f0:0.f) + (rk<21?f1:0.f) + (rk<24?f2:0.f) + (rk<25?f3:0.f);
            cp[d] = Em[c][d] * s;
        }
    }
}

// ---- K4a: out = comb @ v, exact GeLU, store TRANSPOSED g[b][n][192] bf16 ----
// grid (64, 4), block 256
__global__ void k_applyv(const float* __restrict__ dwout, const float* __restrict__ comb,
                         unsigned short* __restrict__ gT){
    __shared__ float cm[6144];
    int tid = threadIdx.x;
    int b = blockIdx.y;
    int n = blockIdx.x*256 + tid;
    #pragma unroll
    for (int j=0;j<24;j++) cm[tid + j*256] = comb[b*6144 + tid + j*256];
    __syncthreads();
    const float* vb = dwout + (size_t)(b*576 + 384)*NP + n;
    unsigned short* gp = gT + (size_t)(b*NP + n)*192;
    #pragma unroll 1
    for (int h=0;h<6;h++){
        float v[32];
        #pragma unroll
        for (int d=0;d<32;d++) v[d] = vb[(size_t)(h*32+d)*NP];
        const float* chp = &cm[h*1024];
        #pragma unroll 1
        for (int cg=0;cg<4;cg++){
            float s[8];
            #pragma unroll
            for (int i=0;i<8;i++){
                const float* crow = chp + (cg*8+i)*32;
                float acc = 0.f;
                #pragma unroll
                for (int d=0;d<32;d++) acc += crow[d]*v[d];
                s[i] = 0.5f*acc*(1.f + erff(acc*0.70710678118654752f));
            }
            u32x4 pk;
            pk.x = pk2(s[0],s[1]); pk.y = pk2(s[2],s[3]);
            pk.z = pk2(s[4],s[5]); pk.w = pk2(s[6],s[7]);
            *(u32x4*)(gp + h*32 + cg*8) = pk;
        }
    }
}

// ---- K4b: proj GEMM at low res (M=192,K=192,N=128/block) + nearest 2x upsample ----
// grid (128, 4), block 256
__global__ void k_proj(const unsigned short* __restrict__ gT, const unsigned short* __restrict__ Pbf,
                       float* __restrict__ out){
    __shared__ unsigned short Al[192*72];
    __shared__ unsigned short Bl[128*72];
    int tid = threadIdx.x;
    int lane = tid & 63, wv = tid >> 6;
    int n16 = lane & 15, quad = lane >> 4;
    int y2 = blockIdx.x, b = blockIdx.y;

    f32x4 acc[3][8];
    #pragma unroll
    for (int j=0;j<3;j++)
      #pragma unroll
      for (int s=0;s<8;s++)
        acc[j][s] = (f32x4){0.f,0.f,0.f,0.f};

    for (int cc=0; cc<3; cc++){
        int ic0 = cc*64;
        #pragma unroll
        for (int j=0;j<6;j++){
            int idx = tid + j*256;
            int r = idx >> 3, g = idx & 7;
            *(u32x4*)&Al[r*72 + g*8] = *(const u32x4*)(Pbf + (r*192 + ic0 + g*8));
        }
        #pragma unroll
        for (int j=0;j<4;j++){
            int idx = tid + j*256;
            int r = idx >> 3, g = idx & 7;
            *(u32x4*)&Bl[r*72 + g*8] =
                *(const u32x4*)(gT + ((size_t)(b*NP + y2*128 + r)*192 + ic0 + g*8));
        }
        __syncthreads();
        #pragma unroll
        for (int kc=0;kc<2;kc++){
            int ko = kc*32 + quad*8;
            bf16x8 af[3], bfr[8];
            #pragma unroll
            for (int j=0;j<3;j++) af[j] = *(const bf16x8*)&Al[((wv*3+j)*16 + n16)*72 + ko];
            #pragma unroll
            for (int s=0;s<8;s++) bfr[s] = *(const bf16x8*)&Bl[(s*16 + n16)*72 + ko];
            #pragma unroll
            for (int j=0;j<3;j++)
              #pragma unroll
              for (int s=0;s<8;s++)
                acc[j][s] = __builtin_amdgcn_mfma_f32_16x16x32_bf16(af[j], bfr[s], acc[j][s], 0,0,0);
        }
        __syncthreads();
    }
    #pragma unroll
    for (int j=0;j<3;j++){
        int oc = (wv*3+j)*16 + quad*4;
        #pragma unroll
        for (int sp=0;sp<8;sp++){
            int x2 = sp*16 + n16;
            #pragma unroll
            for (int r=0;r<4;r++){
                float v = acc[j][sp][r];
                size_t o = ((size_t)(b*192 + oc + r)*256 + 2*y2)*256 + 2*x2;
                float2 val = make_float2(v, v);
                *(float2*)(out + o) = val;
                *(float2*)(out + o + 256) = val;
            }
        }
    }
}

extern "C" void kernel_launch(void* const* d_in, const int* in_sizes, int n_in,
                              void* d_out, int out_size, void* d_ws, size_t ws_size,
                              hipStream_t stream){
    const float* x     = (const float*)d_in[0];
    const float* temp  = (const float*)d_in[1];
    const float* qkvw  = (const float*)d_in[2];
    const float* dww   = (const float*)d_in[3];
    const float* projw = (const float*)d_in[4];
    const float* A1    = (const float*)d_in[5];
    const float* A2    = (const float*)d_in[6];
    const float* A3    = (const float*)d_in[7];
    const float* A4    = (const float*)d_in[8];
    float* out = (float*)d_out;
    char* ws = (char*)d_ws;

    // workspace layout (bytes)
    float*          dwout = (float*)ws;                              // 150,994,944
    unsigned short* qkvp  = (unsigned short*)(ws + 150994944ull);    // 75,497,472
    unsigned short* gT    = (unsigned short*)(ws + 150994944ull);    // overlaps qkvp (dead by then)
    unsigned short* Wbf   = (unsigned short*)(ws + 226492416ull);    // 221,184
    unsigned short* Pbf   = (unsigned short*)(ws + 226713600ull);    // 73,728
    float*          attn  = (float*)(ws + 226787328ull);             // 98,304
    float*          comb  = (float*)(ws + 226885632ull);             // 98,304
    float*          sumsq = (float*)(ws + 226983936ull);             // 6,144

    hipMemsetAsync(attn, 0, 98304, stream);
    hipMemsetAsync(sumsq, 0, 6144, stream);
    k_convert<<<dim3((110592+255)/256), dim3(256), 0, stream>>>(qkvw, Wbf, 110592);
    k_convert<<<dim3((36864+255)/256), dim3(256), 0, stream>>>(projw, Pbf, 36864);
    k_qkvpool<<<dim3(512,4), dim3(256), 0, stream>>>(x, Wbf, qkvp);
    k_dwconv<<<dim3(8,576,4), dim3(256), 0, stream>>>(qkvp, dww, dwout, sumsq);
    k_attnraw<<<dim3(128,6,4), dim3(256), 0, stream>>>(dwout, attn);
    k_mask_softmax<<<dim3(24), dim3(64), 0, stream>>>(attn, sumsq, temp, A1, A2, A3, A4, comb);
    k_applyv<<<dim3(64,4), dim3(256), 0, stream>>>(dwout, comb, gT);
    k_proj<<<dim3(128,4), dim3(256), 0, stream>>>(gT, Pbf, out);
}

// Round 3
// 700.708 us; speedup vs baseline: 1.7783x; 1.0658x over previous
//
#include <hip/hip_runtime.h>
#include <hip/hip_bf16.h>
#include <math.h>

typedef __attribute__((ext_vector_type(8))) short bf16x8;
typedef __attribute__((ext_vector_type(4))) float f32x4;
typedef __attribute__((ext_vector_type(4))) unsigned int u32x4;

#define NP 16384
#define HWFULL 65536

__device__ __forceinline__ unsigned short f2bf(float f){
    union { float f; unsigned int u; } v; v.f = f;
    unsigned int u = v.u;
    u += 0x7fffu + ((u >> 16) & 1u);
    return (unsigned short)(u >> 16);
}
__device__ __forceinline__ float bf2f(unsigned short h){
    union { unsigned int u; float f; } v; v.u = ((unsigned int)h) << 16;
    return v.f;
}
__device__ __forceinline__ unsigned int pk2(float a, float b){
    return (unsigned int)f2bf(a) | ((unsigned int)f2bf(b) << 16);
}

// ---- K0: fp32 -> bf16 weight conversion ----
__global__ void k_convert(const float* __restrict__ s, unsigned short* __restrict__ d, int n){
    int i = blockIdx.x * 256 + threadIdx.x;
    if (i < n) d[i] = f2bf(s[i]);
}

// ---- K1: qkv 1x1 conv (bf16 MFMA GEMM) fused with 2x2 maxpool ----
// v3: A-chunk register prefetch (L2 latency hidden under MFMA), B-stage unroll 6.
// grid (512, 4): bx -> (y2 = bx>>2, x2blk = bx&3); by = b
__global__ __launch_bounds__(256, 2)
void k_qkvpool(const float* __restrict__ x, const unsigned short* __restrict__ Wbf,
               unsigned short* __restrict__ qkvp){
    __shared__ unsigned short Bl[128*200];  // [pos][K=192 + pad8] bf16, persistent
    __shared__ unsigned short Al[192*72];   // [oc][k-chunk 64 + pad8]; aliased as epilogue buffer
    int tid = threadIdx.x;
    int lane = tid & 63, wv = tid >> 6;
    int n16 = lane & 15, quad = lane >> 4;
    int bx = blockIdx.x;
    int y2 = bx >> 2, x2blk = bx & 3;
    int b = blockIdx.y;

    // A-prefetch registers; per-thread r/g fixed across phases
    int ar[6], ag[6];
    #pragma unroll
    for (int j=0;j<6;j++){ int idx = tid + j*256; ar[j] = idx >> 3; ag[j] = idx & 7; }
    u32x4 pre[6];
    // issue first chunk (ocblk=0, cc=0) immediately — lands during B-stage
    #pragma unroll
    for (int j=0;j<6;j++)
        pre[j] = *(const u32x4*)(Wbf + ((0*192 + ar[j])*192 + 0*64 + ag[j]*8));

    // ---- stage B: transpose-gather x[ic][pos] -> Bl[pos][ic], fp32->bf16, full K ----
    #pragma unroll 6
    for (int j=0;j<12;j++){
        int idx = tid + j*256;
        int g = idx >> 7, w = idx & 127;       // g: ic granule of 8; w: 0..63 row y, 64..127 row y+1
        int y = y2*2 + (w >> 6);
        int xc = x2blk*64 + (w & 63);
        const float* xp = x + (size_t)(b*192 + g*8) * HWFULL + y*256 + xc;
        float v0 = xp[0];
        float v1 = xp[(size_t)1*HWFULL];
        float v2 = xp[(size_t)2*HWFULL];
        float v3 = xp[(size_t)3*HWFULL];
        float v4 = xp[(size_t)4*HWFULL];
        float v5 = xp[(size_t)5*HWFULL];
        float v6 = xp[(size_t)6*HWFULL];
        float v7 = xp[(size_t)7*HWFULL];
        u32x4 pk;
        pk.x = pk2(v0,v1); pk.y = pk2(v2,v3); pk.z = pk2(v4,v5); pk.w = pk2(v6,v7);
        *(u32x4*)&Bl[w*200 + g*8] = pk;
    }

    for (int ocblk=0; ocblk<3; ocblk++){
        f32x4 acc[3][8];
        #pragma unroll
        for (int j=0;j<3;j++)
          #pragma unroll
          for (int s=0;s<8;s++)
            acc[j][s] = (f32x4){0.f,0.f,0.f,0.f};

        for (int cc=0; cc<3; cc++){
            __syncthreads();   // prev mfma / epilogue-store reads of Al done before overwrite
            #pragma unroll
            for (int j=0;j<6;j++)
                *(u32x4*)&Al[ar[j]*72 + ag[j]*8] = pre[j];
            __syncthreads();
            // issue next chunk's loads NOW — they retire during the MFMA burst
            int nocb = (cc==2) ? ocblk+1 : ocblk;
            int ncc  = (cc==2) ? 0 : cc+1;
            if (nocb < 3){
                #pragma unroll
                for (int j=0;j<6;j++)
                    pre[j] = *(const u32x4*)(Wbf + ((nocb*192 + ar[j])*192 + ncc*64 + ag[j]*8));
            }
            #pragma unroll
            for (int kc=0;kc<2;kc++){
                int ako = kc*32 + quad*8;
                int bko = cc*64 + ako;
                bf16x8 af[3], bfr[8];
                #pragma unroll
                for (int j=0;j<3;j++) af[j] = *(const bf16x8*)&Al[((wv*3+j)*16 + n16)*72 + ako];
                #pragma unroll
                for (int s=0;s<8;s++) bfr[s] = *(const bf16x8*)&Bl[(s*16 + n16)*200 + bko];
                #pragma unroll
                for (int j=0;j<3;j++)
                  #pragma unroll
                  for (int s=0;s<8;s++)
                    acc[j][s] = __builtin_amdgcn_mfma_f32_16x16x32_bf16(af[j], bfr[s], acc[j][s], 0,0,0);
            }
        }
        __syncthreads();   // all mfma reads done; Al becomes epilogue buffer
        // ---- epilogue: 2x2 maxpool into LDS (strip sp & sp+4 = rows y,y+1; lane^1 = x,x+1)
        unsigned short* Ep = Al;   // [oc 192][36] pooled bf16
        #pragma unroll
        for (int j=0;j<3;j++){
            int ocr = (wv*3+j)*16 + quad*4;
            #pragma unroll
            for (int sp=0;sp<4;sp++){
                #pragma unroll
                for (int r=0;r<4;r++){
                    float v = fmaxf(acc[j][sp][r], acc[j][sp+4][r]);
                    float o = __shfl_xor(v, 1, 64);
                    v = fmaxf(v, o);
                    if ((n16 & 1) == 0)
                        Ep[(ocr + r)*36 + sp*8 + (n16 >> 1)] = f2bf(v);
                }
            }
        }
        __syncthreads();
        // ---- cooperative coalesced store: 192 rows x 32 shorts (64B/row) ----
        size_t rowbase = (size_t)(b*576 + ocblk*192)*NP + y2*128 + x2blk*32;
        #pragma unroll
        for (int it=0; it<6; it++){
            int c = tid + it*256;
            int row = c >> 3, seg = c & 7;
            uint2 vv = *(const uint2*)&Ep[row*36 + seg*4];
            *(uint2*)(qkvp + rowbase + (size_t)row*NP + seg*4) = vv;
        }
    }
}

// ---- K2: depthwise 3x3 SAME conv + per-channel sum-of-squares (q,k only) ----
// grid (8, 576, 4), block 256
__global__ void k_dwconv(const unsigned short* __restrict__ qkvp, const float* __restrict__ dww,
                         float* __restrict__ dwout, float* __restrict__ sumsq){
    __shared__ float sl[18*130];
    int tid = threadIdx.x;
    int y0 = blockIdx.x * 16;
    int ch = blockIdx.y;
    int b  = blockIdx.z;
    const unsigned short* in = qkvp + (size_t)(b*576 + ch) * NP;
    #pragma unroll
    for (int j=0;j<10;j++){
        int idx = tid + j*256;
        if (idx < 18*130){
            int row = idx / 130;
            int col = idx % 130;
            int gy = y0 - 1 + row;
            int gx = col - 1;
            float v = 0.f;
            if (gy >= 0 && gy < 128 && gx >= 0 && gx < 128)
                v = bf2f(in[gy*128 + gx]);
            sl[idx] = v;
        }
    }
    float w0 = dww[ch*9+0], w1 = dww[ch*9+1], w2 = dww[ch*9+2];
    float w3 = dww[ch*9+3], w4 = dww[ch*9+4], w5 = dww[ch*9+5];
    float w6 = dww[ch*9+6], w7 = dww[ch*9+7], w8 = dww[ch*9+8];
    __syncthreads();
    float* outp = dwout + (size_t)(b*576 + ch) * NP;
    int col = tid & 127, half = tid >> 7;
    float ssq = 0.f;
    #pragma unroll
    for (int i=0;i<8;i++){
        int ry = half*8 + i;
        const float* r0 = &sl[ry*130 + col];
        float a = r0[0]*w0   + r0[1]*w1   + r0[2]*w2
                + r0[130]*w3 + r0[131]*w4 + r0[132]*w5
                + r0[260]*w6 + r0[261]*w7 + r0[262]*w8;
        outp[(y0+ry)*128 + col] = a;
        ssq += a*a;
    }
    if (ch < 384){
        #pragma unroll
        for (int off=32; off>0; off>>=1) ssq += __shfl_down(ssq, off, 64);
        if ((tid & 63) == 0) atomicAdd(&sumsq[b*384 + ch], ssq);
    }
}

// ---- K3a: raw attention gram matrix v2 ----
// Transposed [n][34] LDS, float2 frag reads, 4x4 register tiles, wave-per-K-subset,
// in-block reduction, split-K=32 via global atomics.
// grid (32, 6, 4), block 256
__global__ __launch_bounds__(256) void k_attnraw(const float* __restrict__ dwout,
                                                 float* __restrict__ attn){
    __shared__ float sq[128*34];
    __shared__ float sk[128*34];
    int tid = threadIdx.x;
    int n0 = blockIdx.x * 512;
    int h = blockIdx.y, b = blockIdx.z;
    const float* qb = dwout + (size_t)(b*576 + h*32)*NP + n0;
    const float* kb = dwout + (size_t)(b*576 + 192 + h*32)*NP + n0;
    int s = tid >> 6, l = tid & 63;
    int c0 = (l & 7) * 4, d0 = (l >> 3) * 4;
    float acc[4][4];
    #pragma unroll
    for (int i=0;i<4;i++)
      #pragma unroll
      for (int j=0;j<4;j++) acc[i][j] = 0.f;

    for (int slc=0; slc<4; slc++){
        int nb = slc*128;
        __syncthreads();
        #pragma unroll 4
        for (int j=0;j<16;j++){
            int idx = tid + j*256;
            int r = idx >> 7, c = idx & 127;
            sq[c*34 + r] = qb[(size_t)r*NP + nb + c];
            sk[c*34 + r] = kb[(size_t)r*NP + nb + c];
        }
        __syncthreads();
        #pragma unroll 4
        for (int i=0;i<32;i++){
            int n = s*32 + i;
            const float* qp = &sq[n*34];
            const float* kp = &sk[n*34];
            float2 qa = *(const float2*)(qp + c0);
            float2 qc = *(const float2*)(qp + c0 + 2);
            float2 ka = *(const float2*)(kp + d0);
            float2 kc = *(const float2*)(kp + d0 + 2);
            float qv[4] = {qa.x, qa.y, qc.x, qc.y};
            float kv[4] = {ka.x, ka.y, kc.x, kc.y};
            #pragma unroll
            for (int ci=0;ci<4;ci++)
              #pragma unroll
              for (int di=0;di<4;di++)
                acc[ci][di] += qv[ci]*kv[di];
        }
    }
    __syncthreads();
    float* red = sq;   // [s][32][33] partials, 16896 B <= 17408 B
    #pragma unroll
    for (int ci=0;ci<4;ci++)
      #pragma unroll
      for (int di=0;di<4;di++)
        red[(s*32 + c0+ci)*33 + d0+di] = acc[ci][di];
    __syncthreads();
    float* ap = attn + (size_t)(b*6+h)*1024;
    #pragma unroll
    for (int j=0;j<4;j++){
        int o = tid + j*256;
        int c = o >> 5, d = o & 31;
        float v = red[(0*32 + c)*33 + d] + red[(1*32 + c)*33 + d]
                + red[(2*32 + c)*33 + d] + red[(3*32 + c)*33 + d];
        atomicAdd(ap + o, v);
    }
}

// ---- K3b: normalize, temperature, 4x top-k masked softmax, combine with a1..a4 ----
// grid 24, block 64
__global__ void k_mask_softmax(const float* __restrict__ attn, const float* __restrict__ sumsq,
                               const float* __restrict__ temp,
                               const float* __restrict__ A1, const float* __restrict__ A2,
                               const float* __restrict__ A3, const float* __restrict__ A4,
                               float* __restrict__ comb){
    __shared__ float Am[32][33];
    __shared__ float Em[32][33];
    __shared__ float qn[32], kn[32];
    __shared__ unsigned char Rm[32][32];
    int t = threadIdx.x;
    int bh = blockIdx.x;
    int b = bh / 6, h = bh % 6;
    if (t < 32){
        qn[t] = fmaxf(sqrtf(sumsq[b*384 + h*32 + t]), 1e-12f);
        kn[t] = fmaxf(sqrtf(sumsq[b*384 + 192 + h*32 + t]), 1e-12f);
    }
    __syncthreads();
    float tv = temp[h];
    const float* ap = attn + (size_t)bh*1024;
    #pragma unroll
    for (int j=0;j<16;j++){
        int idx = t + j*64;
        int c = idx >> 5, d = idx & 31;
        Am[c][d] = ap[idx] * tv / (qn[c]*kn[d]);
    }
    __syncthreads();
    if (t < 32){
        int c = t;
        float m = -1e30f;
        for (int d=0;d<32;d++) m = fmaxf(m, Am[c][d]);
        for (int d=0;d<32;d++) Em[c][d] = expf(Am[c][d] - m);
        for (int d=0;d<32;d++){
            float ad = Am[c][d];
            int rk = 0;
            for (int dd=0;dd<32;dd++){
                float av = Am[c][dd];
                rk += (av > ad) || (av == ad && dd < d);
            }
            Rm[c][d] = (unsigned char)rk;
        }
        float d0=0,d1=0,d2=0,d3=0;
        for (int d=0;d<32;d++){
            float e = Em[c][d]; int rk = Rm[c][d];
            if (rk < 16) d0 += e;
            if (rk < 21) d1 += e;
            if (rk < 24) d2 += e;
            if (rk < 25) d3 += e;
        }
        float f0 = A1[0]/d0, f1 = A2[0]/d1, f2 = A3[0]/d2, f3 = A4[0]/d3;
        float* cp = comb + (size_t)bh*1024 + c*32;
        for (int d=0;d<32;d++){
            int rk = Rm[c][d];
            float s = (rk<16?f0:0.f) + (rk<21?f1:0.f) + (rk<24?f2:0.f) + (rk<25?f3:0.f);
            cp[d] = Em[c][d] * s;
        }
    }
}

// ---- K4a: out = comb @ v, exact GeLU, store TRANSPOSED g[b][n][192] bf16 ----
// v2: heads split across grid.z (3 per block) -> 512 blocks, 2/CU
// grid (64, 4, 2), block 256
__global__ void k_applyv(const float* __restrict__ dwout, const float* __restrict__ comb,
                         unsigned short* __restrict__ gT){
    __shared__ float cm[3072];
    int tid = threadIdx.x;
    int b = blockIdx.y;
    int hz = blockIdx.z * 3;
    int n = blockIdx.x*256 + tid;
    #pragma unroll
    for (int j=0;j<12;j++) cm[tid + j*256] = comb[b*6144 + hz*1024 + tid + j*256];
    __syncthreads();
    const float* vb = dwout + (size_t)(b*576 + 384 + hz*32)*NP + n;
    unsigned short* gp = gT + (size_t)(b*NP + n)*192 + hz*32;
    #pragma unroll 1
    for (int h=0;h<3;h++){
        float v[32];
        #pragma unroll
        for (int d=0;d<32;d++) v[d] = vb[(size_t)(h*32+d)*NP];
        const float* chp = &cm[h*1024];
        #pragma unroll 1
        for (int cg=0;cg<4;cg++){
            float s[8];
            #pragma unroll
            for (int i=0;i<8;i++){
                const float* crow = chp + (cg*8+i)*32;
                float acc = 0.f;
                #pragma unroll
                for (int d=0;d<32;d++) acc += crow[d]*v[d];
                s[i] = 0.5f*acc*(1.f + erff(acc*0.70710678118654752f));
            }
            u32x4 pk;
            pk.x = pk2(s[0],s[1]); pk.y = pk2(s[2],s[3]);
            pk.z = pk2(s[4],s[5]); pk.w = pk2(s[6],s[7]);
            *(u32x4*)(gp + h*32 + cg*8) = pk;
        }
    }
}

// ---- K4b: proj GEMM at low res (M=192,K=192,N=128/block) + nearest 2x upsample ----
// grid (128, 4), block 256
__global__ void k_proj(const unsigned short* __restrict__ gT, const unsigned short* __restrict__ Pbf,
                       float* __restrict__ out){
    __shared__ unsigned short Al[192*72];
    __shared__ unsigned short Bl[128*72];
    int tid = threadIdx.x;
    int lane = tid & 63, wv = tid >> 6;
    int n16 = lane & 15, quad = lane >> 4;
    int y2 = blockIdx.x, b = blockIdx.y;

    f32x4 acc[3][8];
    #pragma unroll
    for (int j=0;j<3;j++)
      #pragma unroll
      for (int s=0;s<8;s++)
        acc[j][s] = (f32x4){0.f,0.f,0.f,0.f};

    for (int cc=0; cc<3; cc++){
        int ic0 = cc*64;
        #pragma unroll
        for (int j=0;j<6;j++){
            int idx = tid + j*256;
            int r = idx >> 3, g = idx & 7;
            *(u32x4*)&Al[r*72 + g*8] = *(const u32x4*)(Pbf + (r*192 + ic0 + g*8));
        }
        #pragma unroll
        for (int j=0;j<4;j++){
            int idx = tid + j*256;
            int r = idx >> 3, g = idx & 7;
            *(u32x4*)&Bl[r*72 + g*8] =
                *(const u32x4*)(gT + ((size_t)(b*NP + y2*128 + r)*192 + ic0 + g*8));
        }
        __syncthreads();
        #pragma unroll
        for (int kc=0;kc<2;kc++){
            int ko = kc*32 + quad*8;
            bf16x8 af[3], bfr[8];
            #pragma unroll
            for (int j=0;j<3;j++) af[j] = *(const bf16x8*)&Al[((wv*3+j)*16 + n16)*72 + ko];
            #pragma unroll
            for (int s=0;s<8;s++) bfr[s] = *(const bf16x8*)&Bl[(s*16 + n16)*72 + ko];
            #pragma unroll
            for (int j=0;j<3;j++)
              #pragma unroll
              for (int s=0;s<8;s++)
                acc[j][s] = __builtin_amdgcn_mfma_f32_16x16x32_bf16(af[j], bfr[s], acc[j][s], 0,0,0);
        }
        __syncthreads();
    }
    #pragma unroll
    for (int j=0;j<3;j++){
        int oc = (wv*3+j)*16 + quad*4;
        #pragma unroll
        for (int sp=0;sp<8;sp++){
            int x2 = sp*16 + n16;
            #pragma unroll
            for (int r=0;r<4;r++){
                float v = acc[j][sp][r];
                size_t o = ((size_t)(b*192 + oc + r)*256 + 2*y2)*256 + 2*x2;
                float2 val = make_float2(v, v);
                *(float2*)(out + o) = val;
                *(float2*)(out + o + 256) = val;
            }
        }
    }
}

extern "C" void kernel_launch(void* const* d_in, const int* in_sizes, int n_in,
                              void* d_out, int out_size, void* d_ws, size_t ws_size,
                              hipStream_t stream){
    const float* x     = (const float*)d_in[0];
    const float* temp  = (const float*)d_in[1];
    const float* qkvw  = (const float*)d_in[2];
    const float* dww   = (const float*)d_in[3];
    const float* projw = (const float*)d_in[4];
    const float* A1    = (const float*)d_in[5];
    const float* A2    = (const float*)d_in[6];
    const float* A3    = (const float*)d_in[7];
    const float* A4    = (const float*)d_in[8];
    float* out = (float*)d_out;
    char* ws = (char*)d_ws;

    // workspace layout (bytes)
    float*          dwout = (float*)ws;                              // 150,994,944
    unsigned short* qkvp  = (unsigned short*)(ws + 150994944ull);    // 75,497,472
    unsigned short* gT    = (unsigned short*)(ws + 150994944ull);    // overlaps qkvp (dead by then)
    unsigned short* Wbf   = (unsigned short*)(ws + 226492416ull);    // 221,184
    unsigned short* Pbf   = (unsigned short*)(ws + 226713600ull);    // 73,728
    float*          attn  = (float*)(ws + 226787328ull);             // 98,304
    float*          comb  = (float*)(ws + 226885632ull);             // 98,304
    float*          sumsq = (float*)(ws + 226983936ull);             // 6,144

    hipMemsetAsync(attn, 0, 98304, stream);
    hipMemsetAsync(sumsq, 0, 6144, stream);
    k_convert<<<dim3((110592+255)/256), dim3(256), 0, stream>>>(qkvw, Wbf, 110592);
    k_convert<<<dim3((36864+255)/256), dim3(256), 0, stream>>>(projw, Pbf, 36864);
    k_qkvpool<<<dim3(512,4), dim3(256), 0, stream>>>(x, Wbf, qkvp);
    k_dwconv<<<dim3(8,576,4), dim3(256), 0, stream>>>(qkvp, dww, dwout, sumsq);
    k_attnraw<<<dim3(32,6,4), dim3(256), 0, stream>>>(dwout, attn);
    k_mask_softmax<<<dim3(24), dim3(64), 0, stream>>>(attn, sumsq, temp, A1, A2, A3, A4, comb);
    k_applyv<<<dim3(64,4,2), dim3(256), 0, stream>>>(dwout, comb, gT);
    k_proj<<<dim3(128,4), dim3(256), 0, stream>>>(gT, Pbf, out);
}

// Round 4
// 643.488 us; speedup vs baseline: 1.9365x; 1.0889x over previous
//
#include <hip/hip_runtime.h>
#include <hip/hip_bf16.h>
#include <math.h>

typedef __attribute__((ext_vector_type(8))) short bf16x8;
typedef __attribute__((ext_vector_type(4))) float f32x4;
typedef __attribute__((ext_vector_type(4))) unsigned int u32x4;

#define NP 16384
#define HWFULL 65536

__device__ __forceinline__ unsigned short f2bf(float f){
    union { float f; unsigned int u; } v; v.f = f;
    unsigned int u = v.u;
    u += 0x7fffu + ((u >> 16) & 1u);
    return (unsigned short)(u >> 16);
}
__device__ __forceinline__ float bf2f(unsigned short h){
    union { unsigned int u; float f; } v; v.u = ((unsigned int)h) << 16;
    return v.f;
}
__device__ __forceinline__ unsigned int pk2(float a, float b){
    return (unsigned int)f2bf(a) | ((unsigned int)f2bf(b) << 16);
}

// ---- K0: fp32 -> bf16 weight conversion ----
__global__ void k_convert(const float* __restrict__ s, unsigned short* __restrict__ d, int n){
    int i = blockIdx.x * 256 + threadIdx.x;
    if (i < n) d[i] = f2bf(s[i]);
}

// ---- K1: qkv 1x1 conv (bf16 MFMA GEMM) fused with 2x2 maxpool ----
// v4: NO A-LDS staging — A fragments loaded directly from L2-resident Wbf with
// 1-deep register prefetch. K-loop is barrier-free; 7 barriers/block total.
// grid (512, 4): bx -> (y2 = bx>>2, x2blk = bx&3); by = b
__global__ __launch_bounds__(256, 2)
void k_qkvpool(const float* __restrict__ x, const unsigned short* __restrict__ Wbf,
               unsigned short* __restrict__ qkvp){
    __shared__ unsigned short Bl[128*200];  // [pos][K=192 + pad8] bf16, persistent
    __shared__ unsigned short Ep[192*36];   // pooled epilogue buffer
    int tid = threadIdx.x;
    int lane = tid & 63, wv = tid >> 6;
    int n16 = lane & 15, quad = lane >> 4;
    int bx = blockIdx.x;
    int y2 = bx >> 2, x2blk = bx & 3;
    int b = blockIdx.y;

    // ---- stage B: transpose-gather x[ic][pos] -> Bl[pos][ic], fp32->bf16, full K ----
    #pragma unroll 6
    for (int j=0;j<12;j++){
        int idx = tid + j*256;
        int g = idx >> 7, w = idx & 127;       // g: ic granule of 8; w: 0..63 row y, 64..127 row y+1
        int y = y2*2 + (w >> 6);
        int xc = x2blk*64 + (w & 63);
        const float* xp = x + (size_t)(b*192 + g*8) * HWFULL + y*256 + xc;
        float v0 = xp[0];
        float v1 = xp[(size_t)1*HWFULL];
        float v2 = xp[(size_t)2*HWFULL];
        float v3 = xp[(size_t)3*HWFULL];
        float v4 = xp[(size_t)4*HWFULL];
        float v5 = xp[(size_t)5*HWFULL];
        float v6 = xp[(size_t)6*HWFULL];
        float v7 = xp[(size_t)7*HWFULL];
        u32x4 pk;
        pk.x = pk2(v0,v1); pk.y = pk2(v2,v3); pk.z = pk2(v4,v5); pk.w = pk2(v6,v7);
        *(u32x4*)&Bl[w*200 + g*8] = pk;
    }
    // preload A fragments for (ocblk=0, it=0) — independent of LDS
    bf16x8 afc[3], afn[3];
    #pragma unroll
    for (int j=0;j<3;j++)
        afc[j] = *(const bf16x8*)(Wbf + (size_t)(((wv*3+j)*16 + n16)*192 + quad*8));
    __syncthreads();

    for (int ocblk=0; ocblk<3; ocblk++){
        f32x4 acc[3][8];
        #pragma unroll
        for (int j=0;j<3;j++)
          #pragma unroll
          for (int s=0;s<8;s++)
            acc[j][s] = (f32x4){0.f,0.f,0.f,0.f};

        #pragma unroll 1
        for (int it=0; it<6; it++){
            int nocb = (it==5) ? ocblk+1 : ocblk;
            int nit  = (it==5) ? 0 : it+1;
            if (nocb < 3){
                #pragma unroll
                for (int j=0;j<3;j++)
                    afn[j] = *(const bf16x8*)(Wbf +
                        (size_t)((nocb*192 + (wv*3+j)*16 + n16)*192 + nit*32 + quad*8));
            }
            int bko = it*32 + quad*8;
            bf16x8 bfr[8];
            #pragma unroll
            for (int s=0;s<8;s++) bfr[s] = *(const bf16x8*)&Bl[(s*16 + n16)*200 + bko];
            #pragma unroll
            for (int j=0;j<3;j++)
              #pragma unroll
              for (int s=0;s<8;s++)
                acc[j][s] = __builtin_amdgcn_mfma_f32_16x16x32_bf16(afc[j], bfr[s], acc[j][s], 0,0,0);
            #pragma unroll
            for (int j=0;j<3;j++) afc[j] = afn[j];
        }
        __syncthreads();   // prev ocblk's cooperative-store reads of Ep done
        // ---- epilogue: 2x2 maxpool into LDS (strip sp & sp+4 = rows y,y+1; lane^1 = x,x+1)
        #pragma unroll
        for (int j=0;j<3;j++){
            int ocr = (wv*3+j)*16 + quad*4;
            #pragma unroll
            for (int sp=0;sp<4;sp++){
                #pragma unroll
                for (int r=0;r<4;r++){
                    float v = fmaxf(acc[j][sp][r], acc[j][sp+4][r]);
                    float o = __shfl_xor(v, 1, 64);
                    v = fmaxf(v, o);
                    if ((n16 & 1) == 0)
                        Ep[(ocr + r)*36 + sp*8 + (n16 >> 1)] = f2bf(v);
                }
            }
        }
        __syncthreads();
        // ---- cooperative coalesced store: 192 rows x 32 shorts (64B/row) ----
        size_t rowbase = (size_t)(b*576 + ocblk*192)*NP + y2*128 + x2blk*32;
        #pragma unroll
        for (int it=0; it<6; it++){
            int c = tid + it*256;
            int row = c >> 3, seg = c & 7;
            uint2 vv = *(const uint2*)&Ep[row*36 + seg*4];
            *(uint2*)(qkvp + rowbase + (size_t)row*NP + seg*4) = vv;
        }
    }
}

// ---- K2: depthwise 3x3 SAME conv + per-channel sum-of-squares (q,k only) ----
// grid (8, 576, 4), block 256
__global__ void k_dwconv(const unsigned short* __restrict__ qkvp, const float* __restrict__ dww,
                         float* __restrict__ dwout, float* __restrict__ sumsq){
    __shared__ float sl[18*130];
    int tid = threadIdx.x;
    int y0 = blockIdx.x * 16;
    int ch = blockIdx.y;
    int b  = blockIdx.z;
    const unsigned short* in = qkvp + (size_t)(b*576 + ch) * NP;
    #pragma unroll
    for (int j=0;j<10;j++){
        int idx = tid + j*256;
        if (idx < 18*130){
            int row = idx / 130;
            int col = idx % 130;
            int gy = y0 - 1 + row;
            int gx = col - 1;
            float v = 0.f;
            if (gy >= 0 && gy < 128 && gx >= 0 && gx < 128)
                v = bf2f(in[gy*128 + gx]);
            sl[idx] = v;
        }
    }
    float w0 = dww[ch*9+0], w1 = dww[ch*9+1], w2 = dww[ch*9+2];
    float w3 = dww[ch*9+3], w4 = dww[ch*9+4], w5 = dww[ch*9+5];
    float w6 = dww[ch*9+6], w7 = dww[ch*9+7], w8 = dww[ch*9+8];
    __syncthreads();
    float* outp = dwout + (size_t)(b*576 + ch) * NP;
    int col = tid & 127, half = tid >> 7;
    float ssq = 0.f;
    #pragma unroll
    for (int i=0;i<8;i++){
        int ry = half*8 + i;
        const float* r0 = &sl[ry*130 + col];
        float a = r0[0]*w0   + r0[1]*w1   + r0[2]*w2
                + r0[130]*w3 + r0[131]*w4 + r0[132]*w5
                + r0[260]*w6 + r0[261]*w7 + r0[262]*w8;
        outp[(y0+ry)*128 + col] = a;
        ssq += a*a;
    }
    if (ch < 384){
        #pragma unroll
        for (int off=32; off>0; off>>=1) ssq += __shfl_down(ssq, off, 64);
        if ((tid & 63) == 0) atomicAdd(&sumsq[b*384 + ch], ssq);
    }
}

// ---- K3a: raw attention gram matrix v2 ----
// grid (32, 6, 4), block 256
__global__ __launch_bounds__(256) void k_attnraw(const float* __restrict__ dwout,
                                                 float* __restrict__ attn){
    __shared__ float sq[128*34];
    __shared__ float sk[128*34];
    int tid = threadIdx.x;
    int n0 = blockIdx.x * 512;
    int h = blockIdx.y, b = blockIdx.z;
    const float* qb = dwout + (size_t)(b*576 + h*32)*NP + n0;
    const float* kb = dwout + (size_t)(b*576 + 192 + h*32)*NP + n0;
    int s = tid >> 6, l = tid & 63;
    int c0 = (l & 7) * 4, d0 = (l >> 3) * 4;
    float acc[4][4];
    #pragma unroll
    for (int i=0;i<4;i++)
      #pragma unroll
      for (int j=0;j<4;j++) acc[i][j] = 0.f;

    for (int slc=0; slc<4; slc++){
        int nb = slc*128;
        __syncthreads();
        #pragma unroll 4
        for (int j=0;j<16;j++){
            int idx = tid + j*256;
            int r = idx >> 7, c = idx & 127;
            sq[c*34 + r] = qb[(size_t)r*NP + nb + c];
            sk[c*34 + r] = kb[(size_t)r*NP + nb + c];
        }
        __syncthreads();
        #pragma unroll 4
        for (int i=0;i<32;i++){
            int n = s*32 + i;
            const float* qp = &sq[n*34];
            const float* kp = &sk[n*34];
            float2 qa = *(const float2*)(qp + c0);
            float2 qc = *(const float2*)(qp + c0 + 2);
            float2 ka = *(const float2*)(kp + d0);
            float2 kc = *(const float2*)(kp + d0 + 2);
            float qv[4] = {qa.x, qa.y, qc.x, qc.y};
            float kv[4] = {ka.x, ka.y, kc.x, kc.y};
            #pragma unroll
            for (int ci=0;ci<4;ci++)
              #pragma unroll
              for (int di=0;di<4;di++)
                acc[ci][di] += qv[ci]*kv[di];
        }
    }
    __syncthreads();
    float* red = sq;   // [s][32][33] partials
    #pragma unroll
    for (int ci=0;ci<4;ci++)
      #pragma unroll
      for (int di=0;di<4;di++)
        red[(s*32 + c0+ci)*33 + d0+di] = acc[ci][di];
    __syncthreads();
    float* ap = attn + (size_t)(b*6+h)*1024;
    #pragma unroll
    for (int j=0;j<4;j++){
        int o = tid + j*256;
        int c = o >> 5, d = o & 31;
        float v = red[(0*32 + c)*33 + d] + red[(1*32 + c)*33 + d]
                + red[(2*32 + c)*33 + d] + red[(3*32 + c)*33 + d];
        atomicAdd(ap + o, v);
    }
}

// ---- K3b: normalize, temperature, 4x top-k masked softmax, combine with a1..a4 ----
// grid 24, block 64
__global__ void k_mask_softmax(const float* __restrict__ attn, const float* __restrict__ sumsq,
                               const float* __restrict__ temp,
                               const float* __restrict__ A1, const float* __restrict__ A2,
                               const float* __restrict__ A3, const float* __restrict__ A4,
                               float* __restrict__ comb){
    __shared__ float Am[32][33];
    __shared__ float Em[32][33];
    __shared__ float qn[32], kn[32];
    __shared__ unsigned char Rm[32][32];
    int t = threadIdx.x;
    int bh = blockIdx.x;
    int b = bh / 6, h = bh % 6;
    if (t < 32){
        qn[t] = fmaxf(sqrtf(sumsq[b*384 + h*32 + t]), 1e-12f);
        kn[t] = fmaxf(sqrtf(sumsq[b*384 + 192 + h*32 + t]), 1e-12f);
    }
    __syncthreads();
    float tv = temp[h];
    const float* ap = attn + (size_t)bh*1024;
    #pragma unroll
    for (int j=0;j<16;j++){
        int idx = t + j*64;
        int c = idx >> 5, d = idx & 31;
        Am[c][d] = ap[idx] * tv / (qn[c]*kn[d]);
    }
    __syncthreads();
    if (t < 32){
        int c = t;
        float m = -1e30f;
        for (int d=0;d<32;d++) m = fmaxf(m, Am[c][d]);
        for (int d=0;d<32;d++) Em[c][d] = expf(Am[c][d] - m);
        for (int d=0;d<32;d++){
            float ad = Am[c][d];
            int rk = 0;
            for (int dd=0;dd<32;dd++){
                float av = Am[c][dd];
                rk += (av > ad) || (av == ad && dd < d);
            }
            Rm[c][d] = (unsigned char)rk;
        }
        float d0=0,d1=0,d2=0,d3=0;
        for (int d=0;d<32;d++){
            float e = Em[c][d]; int rk = Rm[c][d];
            if (rk < 16) d0 += e;
            if (rk < 21) d1 += e;
            if (rk < 24) d2 += e;
            if (rk < 25) d3 += e;
        }
        float f0 = A1[0]/d0, f1 = A2[0]/d1, f2 = A3[0]/d2, f3 = A4[0]/d3;
        float* cp = comb + (size_t)bh*1024 + c*32;
        for (int d=0;d<32;d++){
            int rk = Rm[c][d];
            float s = (rk<16?f0:0.f) + (rk<21?f1:0.f) + (rk<24?f2:0.f) + (rk<25?f3:0.f);
            cp[d] = Em[c][d] * s;
        }
    }
}

// ---- K4a: out = comb @ v, exact GeLU, store TRANSPOSED g[b][n][192] bf16 ----
// grid (64, 4, 2), block 256
__global__ void k_applyv(const float* __restrict__ dwout, const float* __restrict__ comb,
                         unsigned short* __restrict__ gT){
    __shared__ float cm[3072];
    int tid = threadIdx.x;
    int b = blockIdx.y;
    int hz = blockIdx.z * 3;
    int n = blockIdx.x*256 + tid;
    #pragma unroll
    for (int j=0;j<12;j++) cm[tid + j*256] = comb[b*6144 + hz*1024 + tid + j*256];
    __syncthreads();
    const float* vb = dwout + (size_t)(b*576 + 384 + hz*32)*NP + n;
    unsigned short* gp = gT + (size_t)(b*NP + n)*192 + hz*32;
    #pragma unroll 1
    for (int h=0;h<3;h++){
        float v[32];
        #pragma unroll
        for (int d=0;d<32;d++) v[d] = vb[(size_t)(h*32+d)*NP];
        const float* chp = &cm[h*1024];
        #pragma unroll 1
        for (int cg=0;cg<4;cg++){
            float s[8];
            #pragma unroll
            for (int i=0;i<8;i++){
                const float* crow = chp + (cg*8+i)*32;
                float acc = 0.f;
                #pragma unroll
                for (int d=0;d<32;d++) acc += crow[d]*v[d];
                s[i] = 0.5f*acc*(1.f + erff(acc*0.70710678118654752f));
            }
            u32x4 pk;
            pk.x = pk2(s[0],s[1]); pk.y = pk2(s[2],s[3]);
            pk.z = pk2(s[4],s[5]); pk.w = pk2(s[6],s[7]);
            *(u32x4*)(gp + h*32 + cg*8) = pk;
        }
    }
}

// ---- K4b: proj GEMM at low res + nearest 2x upsample ----
// v2: full-K B staged once (contiguous 98KB), A direct from L2 with prefetch,
// single barrier, direct coalesced stores.
// grid (128, 4), block 256
__global__ __launch_bounds__(256, 2)
void k_proj(const unsigned short* __restrict__ gT, const unsigned short* __restrict__ Pbf,
            float* __restrict__ out){
    __shared__ unsigned short Bl[128*200];  // [pos][K=192 + pad8]
    int tid = threadIdx.x;
    int lane = tid & 63, wv = tid >> 6;
    int n16 = lane & 15, quad = lane >> 4;
    int y2 = blockIdx.x, b = blockIdx.y;

    // ---- stage B once: contiguous 98KB, fully coalesced 16B/lane ----
    #pragma unroll 6
    for (int j=0;j<12;j++){
        int idx = tid + j*256;
        int r = idx / 24, g = idx - r*24;
        *(u32x4*)&Bl[r*200 + g*8] =
            *(const u32x4*)(gT + ((size_t)(b*NP + y2*128 + r)*192 + g*8));
    }
    bf16x8 afc[3], afn[3];
    #pragma unroll
    for (int j=0;j<3;j++)
        afc[j] = *(const bf16x8*)(Pbf + (size_t)(((wv*3+j)*16 + n16)*192 + quad*8));
    __syncthreads();

    f32x4 acc[3][8];
    #pragma unroll
    for (int j=0;j<3;j++)
      #pragma unroll
      for (int s=0;s<8;s++)
        acc[j][s] = (f32x4){0.f,0.f,0.f,0.f};

    #pragma unroll 1
    for (int it=0; it<6; it++){
        if (it < 5){
            #pragma unroll
            for (int j=0;j<3;j++)
                afn[j] = *(const bf16x8*)(Pbf +
                    (size_t)(((wv*3+j)*16 + n16)*192 + (it+1)*32 + quad*8));
        }
        int bko = it*32 + quad*8;
        bf16x8 bfr[8];
        #pragma unroll
        for (int s=0;s<8;s++) bfr[s] = *(const bf16x8*)&Bl[(s*16 + n16)*200 + bko];
        #pragma unroll
        for (int j=0;j<3;j++)
          #pragma unroll
          for (int s=0;s<8;s++)
            acc[j][s] = __builtin_amdgcn_mfma_f32_16x16x32_bf16(afc[j], bfr[s], acc[j][s], 0,0,0);
        #pragma unroll
        for (int j=0;j<3;j++) afc[j] = afn[j];
    }

    #pragma unroll
    for (int j=0;j<3;j++){
        int oc = (wv*3+j)*16 + quad*4;
        #pragma unroll
        for (int sp=0;sp<8;sp++){
            int x2 = sp*16 + n16;
            #pragma unroll
            for (int r=0;r<4;r++){
                float v = acc[j][sp][r];
                size_t o = ((size_t)(b*192 + oc + r)*256 + 2*y2)*256 + 2*x2;
                float2 val = make_float2(v, v);
                *(float2*)(out + o) = val;
                *(float2*)(out + o + 256) = val;
            }
        }
    }
}

extern "C" void kernel_launch(void* const* d_in, const int* in_sizes, int n_in,
                              void* d_out, int out_size, void* d_ws, size_t ws_size,
                              hipStream_t stream){
    const float* x     = (const float*)d_in[0];
    const float* temp  = (const float*)d_in[1];
    const float* qkvw  = (const float*)d_in[2];
    const float* dww   = (const float*)d_in[3];
    const float* projw = (const float*)d_in[4];
    const float* A1    = (const float*)d_in[5];
    const float* A2    = (const float*)d_in[6];
    const float* A3    = (const float*)d_in[7];
    const float* A4    = (const float*)d_in[8];
    float* out = (float*)d_out;
    char* ws = (char*)d_ws;

    // workspace layout (bytes)
    float*          dwout = (float*)ws;                              // 150,994,944
    unsigned short* qkvp  = (unsigned short*)(ws + 150994944ull);    // 75,497,472
    unsigned short* gT    = (unsigned short*)(ws + 150994944ull);    // overlaps qkvp (dead by then)
    unsigned short* Wbf   = (unsigned short*)(ws + 226492416ull);    // 221,184
    unsigned short* Pbf   = (unsigned short*)(ws + 226713600ull);    // 73,728
    float*          attn  = (float*)(ws + 226787328ull);             // 98,304
    float*          comb  = (float*)(ws + 226885632ull);             // 98,304
    float*          sumsq = (float*)(ws + 226983936ull);             // 6,144

    hipMemsetAsync(attn, 0, 98304, stream);
    hipMemsetAsync(sumsq, 0, 6144, stream);
    k_convert<<<dim3((110592+255)/256), dim3(256), 0, stream>>>(qkvw, Wbf, 110592);
    k_convert<<<dim3((36864+255)/256), dim3(256), 0, stream>>>(projw, Pbf, 36864);
    k_qkvpool<<<dim3(512,4), dim3(256), 0, stream>>>(x, Wbf, qkvp);
    k_dwconv<<<dim3(8,576,4), dim3(256), 0, stream>>>(qkvp, dww, dwout, sumsq);
    k_attnraw<<<dim3(32,6,4), dim3(256), 0, stream>>>(dwout, attn);
    k_mask_softmax<<<dim3(24), dim3(64), 0, stream>>>(attn, sumsq, temp, A1, A2, A3, A4, comb);
    k_applyv<<<dim3(64,4,2), dim3(256), 0, stream>>>(dwout, comb, gT);
    k_proj<<<dim3(128,4), dim3(256), 0, stream>>>(gT, Pbf, out);
}